// Round 18
// baseline (350.991 us; speedup 1.0000x reference)
//
#include <hip/hip_runtime.h>
#include <hip/hip_bf16.h>
#include <hip/hip_fp8.h>

#define B_TOTAL 131072

typedef __attribute__((ext_vector_type(8))) short short8;   // 8 bf16 MFMA A/B frag
typedef __attribute__((ext_vector_type(4))) float f32x4;    // MFMA C/D frag
typedef __attribute__((ext_vector_type(16))) unsigned char uchar16;
typedef __attribute__((ext_vector_type(4))) int int4v;
typedef __attribute__((ext_vector_type(8))) int int8v;      // 32B fp8 MX fragment
typedef unsigned int uint;

#define MFMA(a,b,c) __builtin_amdgcn_mfma_f32_16x16x32_bf16(a,b,c,0,0,0)
#define MFMA8(a,b,c) __builtin_amdgcn_mfma_f32_16x16x32_fp8_fp8(a,b,c,0,0,0)
// MX-scaled fp8: K=128, fmt 0 = e4m3, scale bytes 0x7F = 2^0 = 1.0 (exact)
#define MFMAS(a,b,c) __builtin_amdgcn_mfma_scale_f32_16x16x128_f8f6f4( \
    a, b, c, 0, 0, 0, 0x7F7F7F7F, 0, 0x7F7F7F7F)

union V8U { int8v v; int4v h[2]; };

__device__ __forceinline__ short f2bf(float f) {
  union { float f; uint u; } x; x.f = f;
  uint r = x.u + 0x7fffu + ((x.u >> 16) & 1u);  // RTNE
  return (short)(r >> 16);
}
__device__ __forceinline__ unsigned char f2fp8(float v) {
  union { __hip_fp8_e4m3 q; unsigned char b; } u;
  u.q = __hip_fp8_e4m3(v);
  return u.b;
}
// fast tanh: 1 - 2/(exp(2x)+1) via v_exp_f32 + v_rcp_f32
__device__ __forceinline__ float ftanh(float x) {
  float e = __builtin_amdgcn_exp2f(x * 2.8853900817779268f);   // exp(2x)
  return 1.f - 2.f * __builtin_amdgcn_rcpf(e + 1.f);
}

__device__ __forceinline__ void gl_lds16(const void* g, void* l) {
  __builtin_amdgcn_global_load_lds((const __attribute__((address_space(1))) uint*)g,
                                   (__attribute__((address_space(3))) uint*)l, 16, 0, 0);
}
__device__ __forceinline__ int swz8(int c, int r) { return (c & ~7) | ((c ^ r) & 7); }

// ============ merged weight prep ============
// w1r: frag-ordered fp8, rec=(n>>4)*5+(k>>7), 2048B/rec (K 544->640 zero-pad)
// w2r: frag-ordered fp8, rec=(n>>4)*8+(k>>7)
// w3r/w4r: k2 frag order | pwT/qw2T.
__global__ __launch_bounds__(256)
void prep(const float* __restrict__ bw1, const float* __restrict__ bw2,
          const float* __restrict__ bw3, const float* __restrict__ tw2,
          const float* __restrict__ pw, const float* __restrict__ qw2,
          unsigned char* __restrict__ w1r, unsigned char* __restrict__ w2r,
          unsigned char* __restrict__ w3r, short* __restrict__ w4r,
          short* __restrict__ pwT, short* __restrict__ qw2T) {
  __shared__ float tile[32][33];
  int b = blockIdx.x;
  if (b == 1344) {  // small weights, scattered (tiny)
    for (int t = threadIdx.x; t < 6144; t += 256) {
      if (t < 4096) { int c = t >> 8, k = t & 255;
        pwT[t] = (c < 13) ? f2bf(pw[k * 13 + c]) : (short)0; }
      else { int i = t - 4096; int c = i >> 7, j = i & 127;
        qw2T[i] = (c < 13) ? f2bf(qw2[j * 13 + c]) : (short)0; }
    }
    return;
  }
  const float* src; int K, N, mat;
  if (b < 640)       { src = bw1; K = 544;  N = 1024; mat = 0; }
  else if (b < 1152) { b -= 640;  src = bw2; K = 1024; N = 512;  mat = 1; }
  else if (b < 1280) { b -= 1152; src = bw3; K = 512;  N = 256;  mat = 2; }
  else               { b -= 1280; src = tw2; K = 256;  N = 256;  mat = 3; }
  const int ntk = (mat == 0) ? 20 : (mat == 1) ? 32 : (mat == 2) ? 16 : 8;
  const int tn = b / ntk, tk = b % ntk;
  const int k0 = tk * 32, n0 = tn * 32;
  const int tx = threadIdx.x & 31, ty = threadIdx.x >> 5;
#pragma unroll
  for (int rr = 0; rr < 32; rr += 8) {
    int k = k0 + ty + rr;
    tile[ty + rr][tx] = (k < K) ? src[(long)k * N + n0 + tx] : 0.f;
  }
  __syncthreads();
#pragma unroll
  for (int rr = 0; rr < 32; rr += 8) {
    int nl = ty + rr;
    int n = n0 + nl, k = k0 + tx;
    float v = tile[tx][nl];
    if (mat == 0 || mat == 1) {
      const int NTk = (mat == 0) ? 5 : 8;
      unsigned char* dst = (mat == 0) ? w1r : w2r;
      const long rec = (long)(n >> 4) * NTk + (k >> 7);
      const int ln = ((k >> 5) & 3) * 16 + (n & 15);
      dst[rec * 2048 + ln * 32 + (k & 31)] = f2fp8(v);
    } else {
      int ks = k >> 5, fq = (k >> 3) & 3, j = k & 7;
      int wb = n >> 5, hf = (n >> 4) & 1, fr = n & 15;
      long idx = (long)(((ks * 8 + wb) * 2 + hf) * 4 + fq) * 128 + fr * 8 + j;
      if (mat == 2) w3r[idx] = f2fp8(v);
      else          w4r[idx] = f2bf(v);
    }
  }
}

// ---- enc kernel: builds enc[M][640] fp8 (zero-padded cols 544..639) ----
__global__ __launch_bounds__(256)
void enc_k(const float* __restrict__ state, const float* __restrict__ action,
           const float* __restrict__ sensors, unsigned char* __restrict__ enc) {
  __shared__ float sval[64][17];
  __shared__ float wexp[64][32];
  __shared__ float sens[96];
  const int tid = threadIdx.x;
  const int rb = blockIdx.x * 64;
  if (tid < 96) sens[tid] = sensors[tid];
  for (int i = tid; i < 64 * 17; i += 256) {
    const int r = i / 17, c = i % 17;
    const long grow = rb + r;
    sval[r][c] = (c < 13) ? state[grow * 13 + c] : action[grow * 4 + (c - 13)];
  }
  __syncthreads();
  for (int i = tid; i < 64 * 32; i += 256) {
    const int r = i >> 5, s = i & 31;
    const float dx = sens[s*3+0] - sval[r][0];
    const float dy = sens[s*3+1] - sval[r][1];
    const float dz = sens[s*3+2] - sval[r][2];
    wexp[r][s] = __expf(-2.0f * sqrtf(dx*dx + dy*dy + dz*dz));
  }
  __syncthreads();
  for (int i = tid; i < 64 * 40; i += 256) {
    const int r = i / 40, c16 = i % 40;
    uchar16 v;
#pragma unroll
    for (int j = 0; j < 16; ++j) {
      const int k = c16 * 16 + j;
      unsigned char o = 0;
      if (k < 544) { const int s = k / 17, c = k % 17; o = f2fp8(sval[r][c] * wexp[r][s]); }
      v[j] = o;
    }
    *(uchar16*)&enc[((long)(rb + r)) * 640 + c16 * 16] = v;
  }
}

// ---- MX GEMM fp8 -> fp8 (relu): 128x128 tile, BK=128, mfma_scale 16x16x128 ----
// A staged to LDS (dbuf 32KB); B direct to registers from frag-ordered w*r.
// No XCD remap: working set is L3-fit (m160 regime — swizzle costs ~2% here);
// natural row-major bid keeps same-tm blocks consecutive for A-panel locality.
template<int N, int K, int ACT>
__global__ __launch_bounds__(256, 2)
void gemm_mx(const unsigned char* __restrict__ A, const unsigned char* __restrict__ Br,
             const float* __restrict__ bias, unsigned char* __restrict__ C) {
  constexpr int NT = K / 128;
  constexpr int NTN = N / 128;
  __shared__ __align__(16) unsigned char As[2][128 * 128];
  const int tid = threadIdx.x;
  const int wave = tid >> 6;
  const int lane = tid & 63;
  const int tm = blockIdx.x / NTN;
  const int tn = blockIdx.x % NTN;
  const long arow0 = (long)tm * 128;
  const long brow0 = (long)tn * 128;

  const int wr = (wave >> 1) * 64;
  const int wc = (wave & 1) * 64;
  const int fr = lane & 15;
  const int fg = lane >> 4;

  auto stageA = [&](int b, int kt) {
    const int k0 = kt * 128;
#pragma unroll
    for (int it = 0; it < 4; ++it) {       // 1024 chunks
      const int ch = it * 256 + tid;
      const int row = ch >> 3;
      const int cs = (ch & 7) ^ (row & 7); // inverse-swizzled source chunk
      gl_lds16(A + (arow0 + row) * (long)K + k0 + cs * 16, &As[b][ch * 16]);
    }
  };

  // B frag base: ncol16 = (tn*128 + wc + n*16)>>4 = tn*8 + (wc>>4) + n
  const unsigned char* bbase = Br + ((long)(tn * 8 + (wc >> 4)) * NT) * 2048 + lane * 32;
  int8v bvb[2][4];
  auto bload = [&](int buf, int kt) {
#pragma unroll
    for (int n = 0; n < 4; ++n) {
      const unsigned char* p = bbase + ((long)n * NT + kt) * 2048;
      V8U u;
      u.h[0] = *(const int4v*)p;
      u.h[1] = *(const int4v*)(p + 16);
      bvb[buf][n] = u.v;
    }
  };

  f32x4 acc[4][4] = {};

  stageA(0, 0);
  bload(0, 0);
#pragma unroll
  for (int kt = 0; kt < NT; ++kt) {
    const int cur = kt & 1;
    __syncthreads();
    if (kt + 1 < NT) { stageA(cur ^ 1, kt + 1); bload(cur ^ 1, kt + 1); }
    const unsigned char* Ab = As[cur];
    int8v av[4];
#pragma unroll
    for (int m = 0; m < 4; ++m) {
      const int row = wr + m * 16 + fr;
      const int p0 = (2 * fg) ^ (row & 7);
      V8U u;
      u.h[0] = *(const int4v*)&Ab[row * 128 + (p0 << 4)];
      u.h[1] = *(const int4v*)&Ab[row * 128 + ((p0 ^ 1) << 4)];
      av[m] = u.v;
    }
#pragma unroll
    for (int m = 0; m < 4; ++m)
#pragma unroll
      for (int n = 0; n < 4; ++n)
        acc[m][n] = MFMAS(av[m], bvb[cur][n], acc[m][n]);
  }

  float bv[4];
#pragma unroll
  for (int n = 0; n < 4; ++n) bv[n] = bias[tn * 128 + wc + n * 16 + fr];
#pragma unroll
  for (int m = 0; m < 4; ++m)
#pragma unroll
    for (int n = 0; n < 4; ++n) {
      const long col = brow0 + wc + n * 16 + fr;
#pragma unroll
      for (int r = 0; r < 4; ++r) {
        const long row = arow0 + wr + m * 16 + fg * 4 + r;
        float v = acc[m][n][r] + bv[n];
        if (ACT == 1) v = fmaxf(v, 0.f);
        C[row * (long)N + col] = f2fp8(v);
      }
    }
}

// ============ K2 (64 rows/block): branch * trunk -> 13-dim out ============
// Rolling register B-buffers; launch_bounds(512,4); hq inline in proj (round-12 proven).
__global__ __launch_bounds__(512, 4)
void k2(const unsigned char* __restrict__ h2, const float* __restrict__ state,
        const float* __restrict__ tw1, const float* __restrict__ tb1,
        const unsigned char* __restrict__ w3r, const float* __restrict__ bb3,
        const short* __restrict__ w4r, const float* __restrict__ tb2,
        const short* __restrict__ pwT, const float* __restrict__ qw1,
        const short* __restrict__ qw2T, const float* __restrict__ qb1,
        const float* __restrict__ pb, const float* __restrict__ qb2,
        const float* __restrict__ rwp, float* __restrict__ out) {
  __shared__ __align__(16) char lds[77824];
  char*  h2S = lds;                    // [64][512] fp8 (16B-granule XOR swz): 32768
  short* tS  = (short*)(lds + 32768);  // [64][256] bf16 swz8: 32768; later inter
  short* pwS = (short*)(lds + 65536);  // [16][256] swz8: 8192
  short* q2S = (short*)(lds + 73728);  // [16][128] swz8: 4096
  float* prS = (float*)(lds + 16384);  // [64][16] — overlays h2S (dead after branch)
  float* pr2S= (float*)(lds + 20480);  // [64][16]

  const int tid = threadIdx.x, wave = tid >> 6, lane = tid & 63;
  const int fr = lane & 15, fg = lane >> 4;
  const long rb = (long)blockIdx.x * 64;

  // ---- stage h2 panel (pre-swizzled source), pwT, qw2T ----
#pragma unroll
  for (int it = 0; it < 4; ++it) {
    int ch = it * 512 + tid;
    int row = ch >> 5, c = ch & 31;
    gl_lds16(h2 + (rb + row) * 512 + ((c ^ (row & 7)) << 4), h2S + ch * 16);
  }
  { int row = tid >> 5, c = tid & 31;
    gl_lds16(pwT + (long)row * 256 + swz8(c, row) * 8, (char*)pwS + tid * 16); }
  if (tid < 256) { int row = tid >> 4, c = tid & 15;
    gl_lds16(qw2T + (long)row * 128 + swz8(c, row) * 8, (char*)q2S + tid * 16); }

  // ---- initial branch-B rolling buffer (4 deep), issued before t-build ----
  long long bb[4][2];
#pragma unroll
  for (int ks = 0; ks < 4; ++ks) {
    bb[ks][0] = *(const long long*)&w3r[(long)((ks * 8 + wave) * 2 + 0) * 512 + lane * 8];
    bb[ks][1] = *(const long long*)&w3r[(long)((ks * 8 + wave) * 2 + 1) * 512 + lane * 8];
  }

  for (int i = tid; i < 64 * 32; i += 512) {   // t = ftanh(pos @ tw1 + tb1) -> tS
    int r = i >> 5, c8 = i & 31;
    float p0 = state[(rb + r) * 13 + 0], p1 = state[(rb + r) * 13 + 1], p2 = state[(rb + r) * 13 + 2];
    short8 v;
#pragma unroll
    for (int j = 0; j < 8; ++j) {
      int jj = c8 * 8 + j;
      v[j] = f2bf(ftanh(p0 * tw1[jj] + p1 * tw1[256 + jj] + p2 * tw1[512 + jj] + tb1[jj]));
    }
    *(short8*)&tS[(r * 32 + swz8(c8, r)) * 8] = v;
  }
  __syncthreads();   // barrier 1: staging landed, tS built

  // ---- branch gemm: fp8, K=512 — LDS A + 4-deep rolling B pipeline ----
  f32x4 acc3[4][2] = {};
#pragma unroll
  for (int ks = 0; ks < 16; ++ks) {
    long long a[4];
#pragma unroll
    for (int mf = 0; mf < 4; ++mf) {
      int row = mf * 16 + fr;
      int c16 = (ks * 2 + (fg >> 1)) ^ (row & 7);
      a[mf] = *(const long long*)&h2S[row * 512 + (c16 << 4) + ((fg & 1) << 3)];
    }
    const long long c0 = bb[ks & 3][0], c1 = bb[ks & 3][1];
    if (ks + 4 < 16) {
      bb[ks & 3][0] = *(const long long*)&w3r[(long)(((ks + 4) * 8 + wave) * 2 + 0) * 512 + lane * 8];
      bb[ks & 3][1] = *(const long long*)&w3r[(long)(((ks + 4) * 8 + wave) * 2 + 1) * 512 + lane * 8];
    }
#pragma unroll
    for (int mf = 0; mf < 4; ++mf) {
      acc3[mf][0] = MFMA8(a[mf], c0, acc3[mf][0]);
      acc3[mf][1] = MFMA8(a[mf], c1, acc3[mf][1]);
    }
  }

  // ---- trunk gemm: bf16, K=256 — LDS A + 2-deep rolling B pipeline ----
  short8 bb4[2][2];
#pragma unroll
  for (int ks = 0; ks < 2; ++ks) {
    bb4[ks][0] = *(const short8*)&w4r[(long)((ks * 8 + wave) * 2 + 0) * 512 + lane * 8];
    bb4[ks][1] = *(const short8*)&w4r[(long)((ks * 8 + wave) * 2 + 1) * 512 + lane * 8];
  }
  f32x4 accT[4][2] = {};
#pragma unroll
  for (int ks = 0; ks < 8; ++ks) {
    const short8 c0 = bb4[ks & 1][0], c1 = bb4[ks & 1][1];
    if (ks + 2 < 8) {
      bb4[ks & 1][0] = *(const short8*)&w4r[(long)(((ks + 2) * 8 + wave) * 2 + 0) * 512 + lane * 8];
      bb4[ks & 1][1] = *(const short8*)&w4r[(long)(((ks + 2) * 8 + wave) * 2 + 1) * 512 + lane * 8];
    }
#pragma unroll
    for (int mf = 0; mf < 4; ++mf) {
      int row = mf * 16 + fr;
      short8 aF = *(const short8*)&tS[row * 256 + swz8(ks * 4 + fg, row) * 8];
      accT[mf][0] = MFMA(aF, c0, accT[mf][0]);
      accT[mf][1] = MFMA(aF, c1, accT[mf][1]);
    }
  }
  __syncthreads();   // barrier 2: all h2S/tS reads done -> regions reusable

  // ---- interaction -> tS (reuse) ----
#pragma unroll
  for (int nf = 0; nf < 2; ++nf) {
    int col = wave * 32 + nf * 16 + fr;
    float b3 = bb3[col], t2 = tb2[col];
#pragma unroll
    for (int mf = 0; mf < 4; ++mf)
#pragma unroll
      for (int i = 0; i < 4; ++i) {
        int row = mf * 16 + fg * 4 + i;
        float br = acc3[mf][nf][i] + b3;
        float tr = ftanh(accT[mf][nf][i] + t2);
        tS[row * 256 + swz8(col >> 3, row) * 8 + (col & 7)] = f2bf(br * tr);
      }
  }
  __syncthreads();   // barrier 3: inter visible

  // ---- proj: waves 0-3: inter @ pwT (K=256); waves 4-7: inline-hq @ qw2T (K=128) ----
  if (wave < 4) {
    int row = wave * 16 + fr;
    f32x4 accP = {0.f, 0.f, 0.f, 0.f};
#pragma unroll
    for (int ks = 0; ks < 8; ++ks) {
      short8 a = *(const short8*)&tS[row * 256 + swz8(ks * 4 + fg, row) * 8];
      short8 b = *(const short8*)&pwS[fr * 256 + swz8(ks * 4 + fg, fr) * 8];
      accP = MFMA(a, b, accP);
    }
#pragma unroll
    for (int i = 0; i < 4; ++i)
      prS[(wave * 16 + fg * 4 + i) * 16 + fr] = accP[i];
  } else {
    int row = (wave - 4) * 16 + fr;
    float p0 = state[(rb + row) * 13 + 0], p1 = state[(rb + row) * 13 + 1],
          p2 = state[(rb + row) * 13 + 2];
    f32x4 accQ = {0.f, 0.f, 0.f, 0.f};
#pragma unroll
    for (int ks = 0; ks < 4; ++ks) {
      short8 a;
#pragma unroll
      for (int j = 0; j < 8; ++j) {
        int jj = (ks * 4 + fg) * 8 + j;
        float hv = fmaxf(p0 * qw1[jj] + p1 * qw1[128 + jj] + p2 * qw1[256 + jj] + qb1[jj], 0.f);
        a[j] = f2bf(hv);
      }
      short8 b = *(const short8*)&q2S[fr * 128 + swz8(ks * 4 + fg, fr) * 8];
      accQ = MFMA(a, b, accQ);
    }
#pragma unroll
    for (int i = 0; i < 4; ++i)
      pr2S[((wave - 4) * 16 + fg * 4 + i) * 16 + fr] = accQ[i];
  }
  __syncthreads();   // barrier 4

  // ---- epilogue: residual + quat normalize ----
  if (tid < 64) {
    int r = tid;
    float rw = rwp[0];
    float ns[13];
#pragma unroll
    for (int c = 0; c < 13; ++c)
      ns[c] = state[(rb + r) * 13 + c] + rw * (prS[r * 16 + c] + pr2S[r * 16 + c] + pb[c] + qb2[c]);
    float qn = sqrtf(ns[3] * ns[3] + ns[4] * ns[4] + ns[5] * ns[5] + ns[6] * ns[6]) + 1e-8f;
#pragma unroll
    for (int c = 3; c < 7; ++c) ns[c] /= qn;
#pragma unroll
    for (int c = 0; c < 13; ++c) out[(rb + r) * 13 + c] = ns[c];
  }
}

extern "C" void kernel_launch(void* const* d_in, const int* in_sizes, int n_in,
                              void* d_out, int out_size, void* d_ws, size_t ws_size,
                              hipStream_t stream) {
  const float* state  = (const float*)d_in[0];
  const float* action = (const float*)d_in[1];
  const float* sensors= (const float*)d_in[2];
  const float* bw1 = (const float*)d_in[3];
  const float* bb1 = (const float*)d_in[4];
  const float* bw2 = (const float*)d_in[5];
  const float* bb2 = (const float*)d_in[6];
  const float* bw3 = (const float*)d_in[7];
  const float* bb3 = (const float*)d_in[8];
  const float* tw1 = (const float*)d_in[9];
  const float* tb1 = (const float*)d_in[10];
  const float* tw2 = (const float*)d_in[11];
  const float* tb2 = (const float*)d_in[12];
  const float* qw1 = (const float*)d_in[13];
  const float* qb1 = (const float*)d_in[14];
  const float* qw2 = (const float*)d_in[15];
  const float* qb2 = (const float*)d_in[16];
  const float* pw  = (const float*)d_in[17];
  const float* pb  = (const float*)d_in[18];
  const float* rw  = (const float*)d_in[19];
  float* out = (float*)d_out;

  char* p = (char*)d_ws;
  unsigned char* w1r = (unsigned char*)p; p += (size_t)1024 * 640;
  unsigned char* w2r = (unsigned char*)p; p += (size_t)512 * 1024;
  unsigned char* w3r = (unsigned char*)p; p += (size_t)256 * 512;
  short* w4r = (short*)p;          p += (size_t)256 * 256 * 2;
  short* pwT = (short*)p;          p += (size_t)16 * 256 * 2;
  short* qw2T= (short*)p;          p += (size_t)16 * 128 * 2;
  const size_t fixed = (size_t)(p - (char*)d_ws);
  const size_t avail = (ws_size > fixed) ? ws_size - fixed : 0;
  // per-row: enc 640B fp8 (h2 512B overlays after gemm1) + h1f 1024B fp8
  long Mc = (long)(avail / 1664) & ~127L;    // mult of 128 (tile granularity)
  if (Mc > B_TOTAL) Mc = B_TOTAL;
  if (Mc < 128) return;
  unsigned char* encb = (unsigned char*)p;               // Mc*640; h2 overlays
  unsigned char* h2b  = (unsigned char*)p;
  unsigned char* h1f  = (unsigned char*)(p + (size_t)Mc * 640);  // Mc*1024

  prep<<<dim3(1345), dim3(256), 0, stream>>>(bw1, bw2, bw3, tw2, pw, qw2,
                                             w1r, w2r, w3r, w4r, pwT, qw2T);

  for (long r0 = 0; r0 < B_TOTAL; r0 += Mc) {
    long Mr = B_TOTAL - r0; if (Mr > Mc) Mr = Mc;
    enc_k<<<dim3(Mr / 64), dim3(256), 0, stream>>>(state + r0 * 13, action + r0 * 4,
                                                   sensors, encb);
    gemm_mx<1024, 640, 1><<<dim3((Mr / 128) * 8), dim3(256), 0, stream>>>(
        encb, w1r, bb1, h1f);
    gemm_mx<512, 1024, 1><<<dim3((Mr / 128) * 4), dim3(256), 0, stream>>>(
        h1f, w2r, bb2, h2b);
    k2<<<dim3(Mr / 64), dim3(512), 0, stream>>>(h2b, state + r0 * 13, tw1, tb1,
                                                w3r, bb3, w4r, tb2, pwT, qw1, qw2T,
                                                qb1, pb, qb2, rw, out + r0 * 13);
  }
}

// Round 19
// 304.101 us; speedup vs baseline: 1.1542x; 1.1542x over previous
//
#include <hip/hip_runtime.h>
#include <hip/hip_bf16.h>
#include <hip/hip_fp8.h>

#define B_TOTAL 131072

typedef __attribute__((ext_vector_type(8))) short short8;   // 8 bf16 MFMA A/B frag
typedef __attribute__((ext_vector_type(4))) float f32x4;    // MFMA C/D frag
typedef __attribute__((ext_vector_type(16))) unsigned char uchar16;
typedef __attribute__((ext_vector_type(4))) int int4v;
typedef __attribute__((ext_vector_type(8))) int int8v;      // 32B fp8 MX fragment
typedef unsigned int uint;

#define MFMA(a,b,c) __builtin_amdgcn_mfma_f32_16x16x32_bf16(a,b,c,0,0,0)
#define MFMA8(a,b,c) __builtin_amdgcn_mfma_f32_16x16x32_fp8_fp8(a,b,c,0,0,0)
// MX-scaled fp8: K=128, fmt 0 = e4m3, scale bytes 0x7F = 2^0 = 1.0 (exact)
#define MFMAS(a,b,c) __builtin_amdgcn_mfma_scale_f32_16x16x128_f8f6f4( \
    a, b, c, 0, 0, 0, 0x7F7F7F7F, 0, 0x7F7F7F7F)

union V8U { int8v v; int4v h[2]; };

__device__ __forceinline__ short f2bf(float f) {
  union { float f; uint u; } x; x.f = f;
  uint r = x.u + 0x7fffu + ((x.u >> 16) & 1u);  // RTNE
  return (short)(r >> 16);
}
__device__ __forceinline__ unsigned char f2fp8(float v) {
  union { __hip_fp8_e4m3 q; unsigned char b; } u;
  u.q = __hip_fp8_e4m3(v);
  return u.b;
}
// fast tanh: 1 - 2/(exp(2x)+1) via v_exp_f32 + v_rcp_f32
__device__ __forceinline__ float ftanh(float x) {
  float e = __builtin_amdgcn_exp2f(x * 2.8853900817779268f);   // exp(2x)
  return 1.f - 2.f * __builtin_amdgcn_rcpf(e + 1.f);
}

__device__ __forceinline__ void gl_lds16(const void* g, void* l) {
  __builtin_amdgcn_global_load_lds((const __attribute__((address_space(1))) uint*)g,
                                   (__attribute__((address_space(3))) uint*)l, 16, 0, 0);
}
__device__ __forceinline__ int swz8(int c, int r) { return (c & ~7) | ((c ^ r) & 7); }

// ============ merged weight prep ============
// w1r: frag-ordered fp8, rec=(n>>4)*5+(k>>7), 2048B/rec (K 544->640 zero-pad)
// w2r: frag-ordered fp8, rec=(n>>4)*8+(k>>7)
// w3r/w4r: k2 frag order | pwT/qw2T.
__global__ __launch_bounds__(256)
void prep(const float* __restrict__ bw1, const float* __restrict__ bw2,
          const float* __restrict__ bw3, const float* __restrict__ tw2,
          const float* __restrict__ pw, const float* __restrict__ qw2,
          unsigned char* __restrict__ w1r, unsigned char* __restrict__ w2r,
          unsigned char* __restrict__ w3r, short* __restrict__ w4r,
          short* __restrict__ pwT, short* __restrict__ qw2T) {
  __shared__ float tile[32][33];
  int b = blockIdx.x;
  if (b == 1344) {  // small weights, scattered (tiny)
    for (int t = threadIdx.x; t < 6144; t += 256) {
      if (t < 4096) { int c = t >> 8, k = t & 255;
        pwT[t] = (c < 13) ? f2bf(pw[k * 13 + c]) : (short)0; }
      else { int i = t - 4096; int c = i >> 7, j = i & 127;
        qw2T[i] = (c < 13) ? f2bf(qw2[j * 13 + c]) : (short)0; }
    }
    return;
  }
  const float* src; int K, N, mat;
  if (b < 640)       { src = bw1; K = 544;  N = 1024; mat = 0; }
  else if (b < 1152) { b -= 640;  src = bw2; K = 1024; N = 512;  mat = 1; }
  else if (b < 1280) { b -= 1152; src = bw3; K = 512;  N = 256;  mat = 2; }
  else               { b -= 1280; src = tw2; K = 256;  N = 256;  mat = 3; }
  const int ntk = (mat == 0) ? 20 : (mat == 1) ? 32 : (mat == 2) ? 16 : 8;
  const int tn = b / ntk, tk = b % ntk;
  const int k0 = tk * 32, n0 = tn * 32;
  const int tx = threadIdx.x & 31, ty = threadIdx.x >> 5;
#pragma unroll
  for (int rr = 0; rr < 32; rr += 8) {
    int k = k0 + ty + rr;
    tile[ty + rr][tx] = (k < K) ? src[(long)k * N + n0 + tx] : 0.f;
  }
  __syncthreads();
#pragma unroll
  for (int rr = 0; rr < 32; rr += 8) {
    int nl = ty + rr;
    int n = n0 + nl, k = k0 + tx;
    float v = tile[tx][nl];
    if (mat == 0 || mat == 1) {
      const int NTk = (mat == 0) ? 5 : 8;
      unsigned char* dst = (mat == 0) ? w1r : w2r;
      const long rec = (long)(n >> 4) * NTk + (k >> 7);
      const int ln = ((k >> 5) & 3) * 16 + (n & 15);
      dst[rec * 2048 + ln * 32 + (k & 31)] = f2fp8(v);
    } else {
      int ks = k >> 5, fq = (k >> 3) & 3, j = k & 7;
      int wb = n >> 5, hf = (n >> 4) & 1, fr = n & 15;
      long idx = (long)(((ks * 8 + wb) * 2 + hf) * 4 + fq) * 128 + fr * 8 + j;
      if (mat == 2) w3r[idx] = f2fp8(v);
      else          w4r[idx] = f2bf(v);
    }
  }
}

// ---- enc kernel: builds enc[M][640] fp8 (zero-padded cols 544..639) ----
__global__ __launch_bounds__(256)
void enc_k(const float* __restrict__ state, const float* __restrict__ action,
           const float* __restrict__ sensors, unsigned char* __restrict__ enc) {
  __shared__ float sval[64][17];
  __shared__ float wexp[64][32];
  __shared__ float sens[96];
  const int tid = threadIdx.x;
  const int rb = blockIdx.x * 64;
  if (tid < 96) sens[tid] = sensors[tid];
  for (int i = tid; i < 64 * 17; i += 256) {
    const int r = i / 17, c = i % 17;
    const long grow = rb + r;
    sval[r][c] = (c < 13) ? state[grow * 13 + c] : action[grow * 4 + (c - 13)];
  }
  __syncthreads();
  for (int i = tid; i < 64 * 32; i += 256) {
    const int r = i >> 5, s = i & 31;
    const float dx = sens[s*3+0] - sval[r][0];
    const float dy = sens[s*3+1] - sval[r][1];
    const float dz = sens[s*3+2] - sval[r][2];
    wexp[r][s] = __expf(-2.0f * sqrtf(dx*dx + dy*dy + dz*dz));
  }
  __syncthreads();
  for (int i = tid; i < 64 * 40; i += 256) {
    const int r = i / 40, c16 = i % 40;
    uchar16 v;
#pragma unroll
    for (int j = 0; j < 16; ++j) {
      const int k = c16 * 16 + j;
      unsigned char o = 0;
      if (k < 544) { const int s = k / 17, c = k % 17; o = f2fp8(sval[r][c] * wexp[r][s]); }
      v[j] = o;
    }
    *(uchar16*)&enc[((long)(rb + r)) * 640 + c16 * 16] = v;
  }
}

// ---- MX GEMM fp8 -> fp8 (relu): 128x128 tile, BK=128, mfma_scale 16x16x128 ----
// A staged to LDS (dbuf 32KB); B direct to registers from frag-ordered w*r.
// XCD-aware remap REQUIRED: same-tm blocks co-located per XCD keeps A-panel in
// that XCD's L2 (round 18 A/B: removing it -> FETCH 43.6->328 MB, +46us total).
template<int N, int K, int ACT>
__global__ __launch_bounds__(256, 2)
void gemm_mx(const unsigned char* __restrict__ A, const unsigned char* __restrict__ Br,
             const float* __restrict__ bias, unsigned char* __restrict__ C) {
  constexpr int NT = K / 128;
  constexpr int NTN = N / 128;
  __shared__ __align__(16) unsigned char As[2][128 * 128];
  const int tid = threadIdx.x;
  const int wave = tid >> 6;
  const int lane = tid & 63;
  const int Mtiles = gridDim.x / NTN;
  const int bid = blockIdx.x;
  const int xcd = bid & 7, seq = bid >> 3;
  const int tm = xcd * (Mtiles >> 3) + seq / NTN;
  const int tn = seq % NTN;
  const long arow0 = (long)tm * 128;
  const long brow0 = (long)tn * 128;

  const int wr = (wave >> 1) * 64;
  const int wc = (wave & 1) * 64;
  const int fr = lane & 15;
  const int fg = lane >> 4;

  auto stageA = [&](int b, int kt) {
    const int k0 = kt * 128;
#pragma unroll
    for (int it = 0; it < 4; ++it) {       // 1024 chunks
      const int ch = it * 256 + tid;
      const int row = ch >> 3;
      const int cs = (ch & 7) ^ (row & 7); // inverse-swizzled source chunk
      gl_lds16(A + (arow0 + row) * (long)K + k0 + cs * 16, &As[b][ch * 16]);
    }
  };

  // B frag base: ncol16 = (tn*128 + wc + n*16)>>4 = tn*8 + (wc>>4) + n
  const unsigned char* bbase = Br + ((long)(tn * 8 + (wc >> 4)) * NT) * 2048 + lane * 32;
  int8v bvb[2][4];
  auto bload = [&](int buf, int kt) {
#pragma unroll
    for (int n = 0; n < 4; ++n) {
      const unsigned char* p = bbase + ((long)n * NT + kt) * 2048;
      V8U u;
      u.h[0] = *(const int4v*)p;
      u.h[1] = *(const int4v*)(p + 16);
      bvb[buf][n] = u.v;
    }
  };

  f32x4 acc[4][4] = {};

  stageA(0, 0);
  bload(0, 0);
#pragma unroll
  for (int kt = 0; kt < NT; ++kt) {
    const int cur = kt & 1;
    __syncthreads();
    if (kt + 1 < NT) { stageA(cur ^ 1, kt + 1); bload(cur ^ 1, kt + 1); }
    const unsigned char* Ab = As[cur];
    int8v av[4];
#pragma unroll
    for (int m = 0; m < 4; ++m) {
      const int row = wr + m * 16 + fr;
      const int p0 = (2 * fg) ^ (row & 7);
      V8U u;
      u.h[0] = *(const int4v*)&Ab[row * 128 + (p0 << 4)];
      u.h[1] = *(const int4v*)&Ab[row * 128 + ((p0 ^ 1) << 4)];
      av[m] = u.v;
    }
#pragma unroll
    for (int m = 0; m < 4; ++m)
#pragma unroll
      for (int n = 0; n < 4; ++n)
        acc[m][n] = MFMAS(av[m], bvb[cur][n], acc[m][n]);
  }

  float bv[4];
#pragma unroll
  for (int n = 0; n < 4; ++n) bv[n] = bias[tn * 128 + wc + n * 16 + fr];
#pragma unroll
  for (int m = 0; m < 4; ++m)
#pragma unroll
    for (int n = 0; n < 4; ++n) {
      const long col = brow0 + wc + n * 16 + fr;
#pragma unroll
      for (int r = 0; r < 4; ++r) {
        const long row = arow0 + wr + m * 16 + fg * 4 + r;
        float v = acc[m][n][r] + bv[n];
        if (ACT == 1) v = fmaxf(v, 0.f);
        C[row * (long)N + col] = f2fp8(v);
      }
    }
}

// ============ K2 (64 rows/block): branch * trunk -> 13-dim out ============
// Rolling register B-buffers; launch_bounds(512,4); hq inline in proj (round-12 proven).
__global__ __launch_bounds__(512, 4)
void k2(const unsigned char* __restrict__ h2, const float* __restrict__ state,
        const float* __restrict__ tw1, const float* __restrict__ tb1,
        const unsigned char* __restrict__ w3r, const float* __restrict__ bb3,
        const short* __restrict__ w4r, const float* __restrict__ tb2,
        const short* __restrict__ pwT, const float* __restrict__ qw1,
        const short* __restrict__ qw2T, const float* __restrict__ qb1,
        const float* __restrict__ pb, const float* __restrict__ qb2,
        const float* __restrict__ rwp, float* __restrict__ out) {
  __shared__ __align__(16) char lds[77824];
  char*  h2S = lds;                    // [64][512] fp8 (16B-granule XOR swz): 32768
  short* tS  = (short*)(lds + 32768);  // [64][256] bf16 swz8: 32768; later inter
  short* pwS = (short*)(lds + 65536);  // [16][256] swz8: 8192
  short* q2S = (short*)(lds + 73728);  // [16][128] swz8: 4096
  float* prS = (float*)(lds + 16384);  // [64][16] — overlays h2S (dead after branch)
  float* pr2S= (float*)(lds + 20480);  // [64][16]

  const int tid = threadIdx.x, wave = tid >> 6, lane = tid & 63;
  const int fr = lane & 15, fg = lane >> 4;
  const long rb = (long)blockIdx.x * 64;

  // ---- stage h2 panel (pre-swizzled source), pwT, qw2T ----
#pragma unroll
  for (int it = 0; it < 4; ++it) {
    int ch = it * 512 + tid;
    int row = ch >> 5, c = ch & 31;
    gl_lds16(h2 + (rb + row) * 512 + ((c ^ (row & 7)) << 4), h2S + ch * 16);
  }
  { int row = tid >> 5, c = tid & 31;
    gl_lds16(pwT + (long)row * 256 + swz8(c, row) * 8, (char*)pwS + tid * 16); }
  if (tid < 256) { int row = tid >> 4, c = tid & 15;
    gl_lds16(qw2T + (long)row * 128 + swz8(c, row) * 8, (char*)q2S + tid * 16); }

  // ---- initial branch-B rolling buffer (4 deep), issued before t-build ----
  long long bb[4][2];
#pragma unroll
  for (int ks = 0; ks < 4; ++ks) {
    bb[ks][0] = *(const long long*)&w3r[(long)((ks * 8 + wave) * 2 + 0) * 512 + lane * 8];
    bb[ks][1] = *(const long long*)&w3r[(long)((ks * 8 + wave) * 2 + 1) * 512 + lane * 8];
  }

  for (int i = tid; i < 64 * 32; i += 512) {   // t = ftanh(pos @ tw1 + tb1) -> tS
    int r = i >> 5, c8 = i & 31;
    float p0 = state[(rb + r) * 13 + 0], p1 = state[(rb + r) * 13 + 1], p2 = state[(rb + r) * 13 + 2];
    short8 v;
#pragma unroll
    for (int j = 0; j < 8; ++j) {
      int jj = c8 * 8 + j;
      v[j] = f2bf(ftanh(p0 * tw1[jj] + p1 * tw1[256 + jj] + p2 * tw1[512 + jj] + tb1[jj]));
    }
    *(short8*)&tS[(r * 32 + swz8(c8, r)) * 8] = v;
  }
  __syncthreads();   // barrier 1: staging landed, tS built

  // ---- branch gemm: fp8, K=512 — LDS A + 4-deep rolling B pipeline ----
  f32x4 acc3[4][2] = {};
#pragma unroll
  for (int ks = 0; ks < 16; ++ks) {
    long long a[4];
#pragma unroll
    for (int mf = 0; mf < 4; ++mf) {
      int row = mf * 16 + fr;
      int c16 = (ks * 2 + (fg >> 1)) ^ (row & 7);
      a[mf] = *(const long long*)&h2S[row * 512 + (c16 << 4) + ((fg & 1) << 3)];
    }
    const long long c0 = bb[ks & 3][0], c1 = bb[ks & 3][1];
    if (ks + 4 < 16) {
      bb[ks & 3][0] = *(const long long*)&w3r[(long)(((ks + 4) * 8 + wave) * 2 + 0) * 512 + lane * 8];
      bb[ks & 3][1] = *(const long long*)&w3r[(long)(((ks + 4) * 8 + wave) * 2 + 1) * 512 + lane * 8];
    }
#pragma unroll
    for (int mf = 0; mf < 4; ++mf) {
      acc3[mf][0] = MFMA8(a[mf], c0, acc3[mf][0]);
      acc3[mf][1] = MFMA8(a[mf], c1, acc3[mf][1]);
    }
  }

  // ---- trunk gemm: bf16, K=256 — LDS A + 2-deep rolling B pipeline ----
  short8 bb4[2][2];
#pragma unroll
  for (int ks = 0; ks < 2; ++ks) {
    bb4[ks][0] = *(const short8*)&w4r[(long)((ks * 8 + wave) * 2 + 0) * 512 + lane * 8];
    bb4[ks][1] = *(const short8*)&w4r[(long)((ks * 8 + wave) * 2 + 1) * 512 + lane * 8];
  }
  f32x4 accT[4][2] = {};
#pragma unroll
  for (int ks = 0; ks < 8; ++ks) {
    const short8 c0 = bb4[ks & 1][0], c1 = bb4[ks & 1][1];
    if (ks + 2 < 8) {
      bb4[ks & 1][0] = *(const short8*)&w4r[(long)(((ks + 2) * 8 + wave) * 2 + 0) * 512 + lane * 8];
      bb4[ks & 1][1] = *(const short8*)&w4r[(long)(((ks + 2) * 8 + wave) * 2 + 1) * 512 + lane * 8];
    }
#pragma unroll
    for (int mf = 0; mf < 4; ++mf) {
      int row = mf * 16 + fr;
      short8 aF = *(const short8*)&tS[row * 256 + swz8(ks * 4 + fg, row) * 8];
      accT[mf][0] = MFMA(aF, c0, accT[mf][0]);
      accT[mf][1] = MFMA(aF, c1, accT[mf][1]);
    }
  }
  __syncthreads();   // barrier 2: all h2S/tS reads done -> regions reusable

  // ---- interaction -> tS (reuse) ----
#pragma unroll
  for (int nf = 0; nf < 2; ++nf) {
    int col = wave * 32 + nf * 16 + fr;
    float b3 = bb3[col], t2 = tb2[col];
#pragma unroll
    for (int mf = 0; mf < 4; ++mf)
#pragma unroll
      for (int i = 0; i < 4; ++i) {
        int row = mf * 16 + fg * 4 + i;
        float br = acc3[mf][nf][i] + b3;
        float tr = ftanh(accT[mf][nf][i] + t2);
        tS[row * 256 + swz8(col >> 3, row) * 8 + (col & 7)] = f2bf(br * tr);
      }
  }
  __syncthreads();   // barrier 3: inter visible

  // ---- proj: waves 0-3: inter @ pwT (K=256); waves 4-7: inline-hq @ qw2T (K=128) ----
  if (wave < 4) {
    int row = wave * 16 + fr;
    f32x4 accP = {0.f, 0.f, 0.f, 0.f};
#pragma unroll
    for (int ks = 0; ks < 8; ++ks) {
      short8 a = *(const short8*)&tS[row * 256 + swz8(ks * 4 + fg, row) * 8];
      short8 b = *(const short8*)&pwS[fr * 256 + swz8(ks * 4 + fg, fr) * 8];
      accP = MFMA(a, b, accP);
    }
#pragma unroll
    for (int i = 0; i < 4; ++i)
      prS[(wave * 16 + fg * 4 + i) * 16 + fr] = accP[i];
  } else {
    int row = (wave - 4) * 16 + fr;
    float p0 = state[(rb + row) * 13 + 0], p1 = state[(rb + row) * 13 + 1],
          p2 = state[(rb + row) * 13 + 2];
    f32x4 accQ = {0.f, 0.f, 0.f, 0.f};
#pragma unroll
    for (int ks = 0; ks < 4; ++ks) {
      short8 a;
#pragma unroll
      for (int j = 0; j < 8; ++j) {
        int jj = (ks * 4 + fg) * 8 + j;
        float hv = fmaxf(p0 * qw1[jj] + p1 * qw1[128 + jj] + p2 * qw1[256 + jj] + qb1[jj], 0.f);
        a[j] = f2bf(hv);
      }
      short8 b = *(const short8*)&q2S[fr * 128 + swz8(ks * 4 + fg, fr) * 8];
      accQ = MFMA(a, b, accQ);
    }
#pragma unroll
    for (int i = 0; i < 4; ++i)
      pr2S[((wave - 4) * 16 + fg * 4 + i) * 16 + fr] = accQ[i];
  }
  __syncthreads();   // barrier 4

  // ---- epilogue: residual + quat normalize ----
  if (tid < 64) {
    int r = tid;
    float rw = rwp[0];
    float ns[13];
#pragma unroll
    for (int c = 0; c < 13; ++c)
      ns[c] = state[(rb + r) * 13 + c] + rw * (prS[r * 16 + c] + pr2S[r * 16 + c] + pb[c] + qb2[c]);
    float qn = sqrtf(ns[3] * ns[3] + ns[4] * ns[4] + ns[5] * ns[5] + ns[6] * ns[6]) + 1e-8f;
#pragma unroll
    for (int c = 3; c < 7; ++c) ns[c] /= qn;
#pragma unroll
    for (int c = 0; c < 13; ++c) out[(rb + r) * 13 + c] = ns[c];
  }
}

extern "C" void kernel_launch(void* const* d_in, const int* in_sizes, int n_in,
                              void* d_out, int out_size, void* d_ws, size_t ws_size,
                              hipStream_t stream) {
  const float* state  = (const float*)d_in[0];
  const float* action = (const float*)d_in[1];
  const float* sensors= (const float*)d_in[2];
  const float* bw1 = (const float*)d_in[3];
  const float* bb1 = (const float*)d_in[4];
  const float* bw2 = (const float*)d_in[5];
  const float* bb2 = (const float*)d_in[6];
  const float* bw3 = (const float*)d_in[7];
  const float* bb3 = (const float*)d_in[8];
  const float* tw1 = (const float*)d_in[9];
  const float* tb1 = (const float*)d_in[10];
  const float* tw2 = (const float*)d_in[11];
  const float* tb2 = (const float*)d_in[12];
  const float* qw1 = (const float*)d_in[13];
  const float* qb1 = (const float*)d_in[14];
  const float* qw2 = (const float*)d_in[15];
  const float* qb2 = (const float*)d_in[16];
  const float* pw  = (const float*)d_in[17];
  const float* pb  = (const float*)d_in[18];
  const float* rw  = (const float*)d_in[19];
  float* out = (float*)d_out;

  char* p = (char*)d_ws;
  unsigned char* w1r = (unsigned char*)p; p += (size_t)1024 * 640;
  unsigned char* w2r = (unsigned char*)p; p += (size_t)512 * 1024;
  unsigned char* w3r = (unsigned char*)p; p += (size_t)256 * 512;
  short* w4r = (short*)p;          p += (size_t)256 * 256 * 2;
  short* pwT = (short*)p;          p += (size_t)16 * 256 * 2;
  short* qw2T= (short*)p;          p += (size_t)16 * 128 * 2;
  const size_t fixed = (size_t)(p - (char*)d_ws);
  const size_t avail = (ws_size > fixed) ? ws_size - fixed : 0;
  // per-row: enc 640B fp8 (h2 512B overlays after gemm1) + h1f 1024B fp8
  long Mc = (long)(avail / 1664) & ~1023L;   // mult of 1024 (XCD remap: Mtiles%8==0)
  if (Mc > B_TOTAL) Mc = B_TOTAL;
  if (Mc < 1024) return;
  unsigned char* encb = (unsigned char*)p;               // Mc*640; h2 overlays
  unsigned char* h2b  = (unsigned char*)p;
  unsigned char* h1f  = (unsigned char*)(p + (size_t)Mc * 640);  // Mc*1024

  prep<<<dim3(1345), dim3(256), 0, stream>>>(bw1, bw2, bw3, tw2, pw, qw2,
                                             w1r, w2r, w3r, w4r, pwT, qw2T);

  for (long r0 = 0; r0 < B_TOTAL; r0 += Mc) {
    long Mr = B_TOTAL - r0; if (Mr > Mc) Mr = Mc;
    enc_k<<<dim3(Mr / 64), dim3(256), 0, stream>>>(state + r0 * 13, action + r0 * 4,
                                                   sensors, encb);
    gemm_mx<1024, 640, 1><<<dim3((Mr / 128) * 8), dim3(256), 0, stream>>>(
        encb, w1r, bb1, h1f);
    gemm_mx<512, 1024, 1><<<dim3((Mr / 128) * 4), dim3(256), 0, stream>>>(
        h1f, w2r, bb2, h2b);
    k2<<<dim3(Mr / 64), dim3(512), 0, stream>>>(h2b, state + r0 * 13, tw1, tb1,
                                                w3r, bb3, w4r, tb2, pwT, qw1, qw2T,
                                                qb1, pb, qb2, rw, out + r0 * 13);
  }
}